// Round 5
// baseline (290.165 us; speedup 1.0000x reference)
//
#include <hip/hip_runtime.h>
#include <hip/hip_cooperative_groups.h>
#include <math.h>

namespace cg = cooperative_groups;

#define DIM 128
#define NATOMS 8192
#define LPROT 8192
#define CAP 64
#define NF (NATOMS*DIM)
#define NB 256
#define RPB 32
#define TPB 1024

// =================== device phase functions (shared by coop + fallback) ===================

// ELL build for own 32 rows; 16 waves x 2 rows; ballot compaction
__device__ __forceinline__ void d_ell(int blk, int tid, const float* __restrict__ adj,
                                      int* __restrict__ ell, int* __restrict__ cnt) {
  int wv = tid >> 6, lane = tid & 63;
  for (int rr = 0; rr < 2; ++rr) {
    int row = blk * RPB + wv * 2 + rr;
    const float4* rp = (const float4*)(adj + (size_t)row * NATOMS);
    int* er = ell + (size_t)row * CAP;
    int c = 0;
    for (int it = 0; it < NATOMS / 256; ++it) {
      float4 v = rp[(size_t)it * 64 + lane];
      float f[4] = {v.x, v.y, v.z, v.w};
      #pragma unroll
      for (int j = 0; j < 4; ++j) {
        bool nz = (f[j] != 0.0f);
        unsigned long long m = __ballot(nz);
        if (nz) {
          int pos = c + __popcll(m & ((1ull << lane) - 1ull));
          if (pos < CAP) er[pos] = it * 256 + lane * 4 + j;
        }
        c += __popcll(m);
      }
    }
    if (lane == 0) cnt[row] = c > CAP ? CAP : c;
  }
}

// stage W^T (row-major [k][j], 128x128 global) into LDS [128][132]
__device__ __forceinline__ void d_stage_w(int tid, const float* __restrict__ WT, float* Ws) {
  for (int i = tid; i < 4096; i += TPB) {
    int r = i >> 5, c = i & 31;
    *(float4*)&Ws[r * 132 + c * 4] = *(const float4*)&WT[r * DIM + c * 4];
  }
}

// stage own 32 rows of A into LDS [32][132]
__device__ __forceinline__ void d_stage_a(int tid, const float* __restrict__ A,
                                          size_t rbase, float* As) {
  for (int i = tid; i < 1024; i += TPB) {
    int r = i >> 5, c = i & 31;
    *(float4*)&As[r * 132 + c * 4] = *(const float4*)&A[(rbase + r) * DIM + c * 4];
  }
}

// 256-thread 4x4-tile gemm: out[r][j] = relu(sum_k As[r][k]*Ws[k][j] + bias[j])
__device__ __forceinline__ void d_gemm44(int tid, const float* As, const float* Ws,
                                         const float* __restrict__ bias,
                                         float* out, int ostr, size_t obase) {
  if (tid < 256) {
    int j0 = (tid & 31) * 4, r0 = (tid >> 5) * 4;
    float acc[4][4];
    float4 b4 = *(const float4*)&bias[j0];
    #pragma unroll
    for (int ri = 0; ri < 4; ++ri) {
      acc[ri][0] = b4.x; acc[ri][1] = b4.y; acc[ri][2] = b4.z; acc[ri][3] = b4.w;
    }
    for (int k4 = 0; k4 < 32; ++k4) {
      float a[4][4], w[4][4];
      #pragma unroll
      for (int ri = 0; ri < 4; ++ri)
        *(float4*)a[ri] = *(const float4*)&As[(r0 + ri) * 132 + k4 * 4];
      #pragma unroll
      for (int kk = 0; kk < 4; ++kk)
        *(float4*)w[kk] = *(const float4*)&Ws[(k4 * 4 + kk) * 132 + j0];
      #pragma unroll
      for (int ri = 0; ri < 4; ++ri)
        #pragma unroll
        for (int kk = 0; kk < 4; ++kk) {
          acc[ri][0] += a[ri][kk] * w[kk][0];
          acc[ri][1] += a[ri][kk] * w[kk][1];
          acc[ri][2] += a[ri][kk] * w[kk][2];
          acc[ri][3] += a[ri][kk] * w[kk][3];
        }
    }
    #pragma unroll
    for (int ri = 0; ri < 4; ++ri) {
      float4 o;
      o.x = fmaxf(acc[ri][0], 0.f); o.y = fmaxf(acc[ri][1], 0.f);
      o.z = fmaxf(acc[ri][2], 0.f); o.w = fmaxf(acc[ri][3], 0.f);
      *(float4*)&out[(obase + r0 + ri) * (size_t)ostr + j0] = o;
    }
  }
}

// spmv over own 32 rows: xs[row] += sum of neighbor hs rows; 16 waves x 2 rows
__device__ __forceinline__ void d_spmv(int blk, int tid, const int* __restrict__ ell,
                                       const int* __restrict__ cnt,
                                       const float* __restrict__ hs, float* __restrict__ xs) {
  int wv = tid >> 6, lane = tid & 63;
  for (int rr = 0; rr < 2; ++rr) {
    size_t row = (size_t)blk * RPB + wv * 2 + rr;
    int n = cnt[row];
    const int* er = ell + row * CAP;
    float2 a2 = *(const float2*)&xs[row * DIM + lane * 2];
    int t = 0;
    for (; t + 4 <= n; t += 4) {
      int j0 = er[t], j1 = er[t + 1], j2 = er[t + 2], j3 = er[t + 3];
      float2 h0 = *(const float2*)&hs[(size_t)j0 * DIM + lane * 2];
      float2 h1 = *(const float2*)&hs[(size_t)j1 * DIM + lane * 2];
      float2 h2 = *(const float2*)&hs[(size_t)j2 * DIM + lane * 2];
      float2 h3 = *(const float2*)&hs[(size_t)j3 * DIM + lane * 2];
      a2.x += (h0.x + h1.x) + (h2.x + h3.x);
      a2.y += (h0.y + h1.y) + (h2.y + h3.y);
    }
    for (; t < n; ++t) {
      float2 h = *(const float2*)&hs[(size_t)er[t] * DIM + lane * 2];
      a2.x += h.x; a2.y += h.y;
    }
    *(float2*)&xs[row * DIM + lane * 2] = a2;
  }
}

// column-sum of own 32 rows -> atomicAdd into dst[128]; red = 8*128 shared
__device__ __forceinline__ void d_colsum(int blk, int tid, const float* __restrict__ src,
                                         float* red, float* __restrict__ dst) {
  int c = tid & 127, h = tid >> 7;
  size_t rbase = (size_t)blk * RPB;
  float s = 0.f;
  for (int r = h; r < RPB; r += 8) s += src[(rbase + r) * DIM + c];
  red[h * DIM + c] = s;
  __syncthreads();
  if (h == 0) {
    float t2 = 0.f;
    #pragma unroll
    for (int w = 0; w < 8; ++w) t2 += red[w * DIM + c];
    atomicAdd(&dst[c], t2);
  }
}

// x-chain: 3x relu(x @ Wa^T + ba) -> xall[0..2]; xb = shared >=128
__device__ __forceinline__ void d_xchain(int tid, const float* __restrict__ xc,
                                         const float* __restrict__ WaT,
                                         const float* __restrict__ ba,
                                         float* xb, float* __restrict__ xall) {
  if (tid < DIM) xb[tid] = xc[tid];
  __syncthreads();
  for (int i = 0; i < 3; ++i) {
    float a = 0.f;
    if (tid < DIM) {
      a = ba[tid];
      for (int k = 0; k < DIM; ++k) a += xb[k] * WaT[k * DIM + tid];
      a = fmaxf(a, 0.f);
    }
    __syncthreads();
    if (tid < DIM) { xb[tid] = a; xall[i * DIM + tid] = a; }
    __syncthreads();
  }
}

// stage conv input tile (54x156 zero-padded) + weights
__device__ __forceinline__ void d_stage_tile(int blk, int tid, const float* __restrict__ cur,
                                             const float* __restrict__ cwl,
                                             float* U, float* wl) {
  for (int i = tid; i < 529; i += TPB) wl[i] = cwl[i];
  int l0 = blk * RPB;
  for (int i = tid; i < 54 * 156; i += TPB) {
    int ll = i / 156, dd = i % 156;
    int gl = l0 - 11 + ll, gd = dd - 11;
    float v = 0.f;
    if (gl >= 0 && gl < LPROT && (unsigned)gd < DIM)
      v = cur[(size_t)gl * DIM + gd];
    U[i] = v;
  }
}

// 23x23 conv: thread -> row (tid>>5), 4 cols at (tid&31)*4; writes relu to As[32][132]
__device__ __forceinline__ void d_conv(int tid, const float* U, const float* wl,
                                       float cbias, float* As) {
  int ro = tid >> 5, d0 = (tid & 31) * 4;
  float acc[4] = {0.f, 0.f, 0.f, 0.f};
  for (int a = 0; a < 23; ++a) {
    float r[26];
    #pragma unroll
    for (int q = 0; q < 6; ++q)
      *(float4*)&r[4 * q] = *(const float4*)&U[(ro + a) * 156 + d0 + 4 * q];
    r[24] = U[(ro + a) * 156 + d0 + 24];
    r[25] = U[(ro + a) * 156 + d0 + 25];
    #pragma unroll
    for (int b = 0; b < 23; ++b) {
      float wb = wl[a * 23 + b];
      #pragma unroll
      for (int m = 0; m < 4; ++m) acc[m] += r[b + m] * wb;
    }
  }
  #pragma unroll
  for (int m = 0; m < 4; ++m)
    As[ro * 132 + d0 + m] = fmaxf(acc[m] + cbias, 0.f);
}

// attention: weights = tanh(x . hs2_row); write nxt (or accumulate colsum -> xp if last)
__device__ __forceinline__ void d_attn(int blk, int tid, const float* hs2, const float* xrow,
                                       float* __restrict__ nxt, int last,
                                       float* red, float* __restrict__ xp) {
  int wv = tid >> 6, lane = tid & 63;
  size_t rbase = (size_t)blk * RPB;
  float x0 = xrow[lane * 2], x1 = xrow[lane * 2 + 1];
  float cx = 0.f, cy = 0.f;
  #pragma unroll
  for (int rr = 0; rr < 2; ++rr) {
    int row = wv * 2 + rr;
    float2 h = *(const float2*)&hs2[row * 132 + lane * 2];
    float p = h.x * x0 + h.y * x1;
    #pragma unroll
    for (int s = 32; s > 0; s >>= 1) p += __shfl_xor(p, s, 64);
    float wgt = tanhf(p);
    if (!last) {
      float2 o; o.x = wgt * h.x; o.y = wgt * h.y;
      *(float2*)&nxt[(rbase + row) * DIM + lane * 2] = o;
    } else { cx += wgt * h.x; cy += wgt * h.y; }
  }
  if (last) {
    red[wv * DIM + lane * 2] = cx;
    red[wv * DIM + lane * 2 + 1] = cy;
    __syncthreads();
    if (wv == 0) {
      float sx = 0.f, sy = 0.f;
      #pragma unroll
      for (int w = 0; w < 16; ++w) {
        sx += red[w * DIM + lane * 2];
        sy += red[w * DIM + lane * 2 + 1];
      }
      atomicAdd(&xp[lane * 2], sx);
      atomicAdd(&xp[lane * 2 + 1], sy);
    }
  }
}

// final softmax([xc|xp] @ Wo^T + bo) -> out[2]; fs = shared >=32
__device__ __forceinline__ void d_final(int tid, const float* __restrict__ xc,
                                        const float* __restrict__ xp,
                                        const float* __restrict__ Wo,
                                        const float* __restrict__ bo,
                                        float* fs, float* __restrict__ out) {
  int wv = tid >> 6, lane = tid & 63;
  float p0 = 0.f, p1 = 0.f;
  if (tid < 256) {
    float y = (tid < DIM) ? xc[tid] : xp[tid - DIM];
    p0 = y * Wo[tid];
    p1 = y * Wo[256 + tid];
  }
  #pragma unroll
  for (int s = 32; s > 0; s >>= 1) { p0 += __shfl_xor(p0, s, 64); p1 += __shfl_xor(p1, s, 64); }
  if (tid < 256 && lane == 0) { fs[wv] = p0; fs[16 + wv] = p1; }
  __syncthreads();
  if (tid == 0) {
    float l0 = bo[0], l1 = bo[1];
    #pragma unroll
    for (int w = 0; w < 4; ++w) { l0 += fs[w]; l1 += fs[16 + w]; }
    float m = fmaxf(l0, l1);
    float e0 = expf(l0 - m), e1 = expf(l1 - m);
    out[0] = e0 / (e0 + e1);
    out[1] = e1 / (e0 + e1);
  }
}

// =================== prep (plain, r3-proven): gathers + transposes + zero ===================
__global__ __launch_bounds__(256) void k_prep(
    const int* __restrict__ fp, const int* __restrict__ words,
    const float* __restrict__ emb_fp, const float* __restrict__ emb_w,
    const float* __restrict__ Wg, const float* __restrict__ Wa,
    float* __restrict__ xs, float* __restrict__ xsp,
    float* __restrict__ WgT, float* __restrict__ WaT,
    float* __restrict__ xc, float* __restrict__ xp) {
  int b = blockIdx.x, tid = threadIdx.x;
  if (b < 1024) {
    int i = b * 256 + tid;
    int row = i >> 5, c4 = i & 31;
    ((float4*)(xs + (size_t)row * DIM))[c4] =
        ((const float4*)(emb_fp + (size_t)fp[row] * DIM))[c4];
  } else if (b < 2048) {
    int i = (b - 1024) * 256 + tid;
    int row = i >> 5, c4 = i & 31;
    ((float4*)(xsp + (size_t)row * DIM))[c4] =
        ((const float4*)(emb_w + (size_t)words[row] * DIM))[c4];
  } else if (b < 2112) {
    __shared__ float tile[32][33];
    int sub = b - 2048;
    int m = sub >> 4, t = sub & 15;
    int tx = t & 3, ty = t >> 2;
    const float* src = (m < 3) ? Wg + m * DIM * DIM : Wa;
    float*       dst = (m < 3) ? WgT + m * DIM * DIM : WaT;
    int x = tid & 31, y0 = tid >> 5;
    int xg = tx * 32 + x;
    for (int i = y0; i < 32; i += 8)
      tile[i][x] = src[(ty * 32 + i) * DIM + xg];
    __syncthreads();
    int xo = ty * 32 + x;
    for (int i = y0; i < 32; i += 8)
      dst[(tx * 32 + i) * DIM + xo] = tile[x][i];
  } else {
    if (tid < DIM) { xc[tid] = 0.f; xp[tid] = 0.f; }
  }
}

// =================== cooperative GNN: ELL + 3x(gemm->gs->spmv) + colsum + xchain ===================
__global__ __launch_bounds__(TPB, 4) void kg(
    const float* __restrict__ adj, const float* __restrict__ WgT,
    const float* __restrict__ bg, const float* __restrict__ WaT,
    const float* __restrict__ ba, int* __restrict__ ell, int* __restrict__ cnt,
    float* __restrict__ xs, float* __restrict__ hsbA, float* __restrict__ hsbB,
    float* __restrict__ xc, float* __restrict__ xall) {
  cg::grid_group grid = cg::this_grid();
  __shared__ float Ws[128 * 132];
  __shared__ float As[32 * 132];
  __shared__ float red[8 * DIM];
  int tid = threadIdx.x, blk = blockIdx.x;
  size_t rbase = (size_t)blk * RPB;

  d_ell(blk, tid, adj, ell, cnt);        // own rows only -> block-local dependency
  __syncthreads();
  for (int layer = 0; layer < 3; ++layer) {
    float* hout = (layer == 1) ? hsbB : hsbA;   // alternate to avoid WAR across gs
    d_stage_w(tid, WgT + (size_t)layer * DIM * DIM, Ws);
    d_stage_a(tid, xs, rbase, As);
    __syncthreads();
    d_gemm44(tid, As, Ws, bg + layer * DIM, hout, DIM, rbase);
    grid.sync();                          // all hs rows visible
    d_spmv(blk, tid, ell, cnt, hout, xs); // updates own xs rows only
    __syncthreads();
  }
  d_colsum(blk, tid, xs, red, xc);
  grid.sync();
  if (blk == 0) d_xchain(tid, xc, WaT, ba, red, xall);
}

// =================== cooperative protein chain: 3x(conv->gemm->attn) + final ===================
__global__ __launch_bounds__(TPB, 4) void kp(
    const float* __restrict__ cw, const float* __restrict__ cb,
    const float* __restrict__ WaT, const float* __restrict__ ba,
    const float* __restrict__ xall, const float* __restrict__ xc,
    const float* __restrict__ Wo, const float* __restrict__ bo,
    float* __restrict__ bufA, float* __restrict__ bufB,
    float* __restrict__ xp, float* __restrict__ out) {
  cg::grid_group grid = cg::this_grid();
  __shared__ float U[128 * 132];   // union: conv tile (54*156=8424) / Ws (16896)
  __shared__ float wl[529];
  __shared__ float As[32 * 132];
  __shared__ float hs2[32 * 132];
  __shared__ float xrow[DIM];
  __shared__ float fs[32];
  int tid = threadIdx.x, blk = blockIdx.x;

  const float* cur = bufA;
  float* nxt = bufB;
  for (int layer = 0; layer < 3; ++layer) {
    d_stage_tile(blk, tid, cur, cw + layer * 529, U, wl);
    if (tid < DIM) xrow[tid] = xall[layer * DIM + tid];
    __syncthreads();
    d_conv(tid, U, wl, cb[layer], As);
    __syncthreads();                 // conv done reading U
    d_stage_w(tid, WaT, U);          // overwrite tile with Wa^T
    __syncthreads();
    d_gemm44(tid, As, U, ba, hs2, 132, 0);
    __syncthreads();
    d_attn(blk, tid, hs2, xrow, nxt, layer == 2, As, xp);
    grid.sync();                     // halo rows of nxt ready / xp complete
    const float* t = cur; cur = nxt; nxt = (float*)t;
  }
  if (blk == 0) d_final(tid, xc, xp, Wo, bo, fs, out);
}

// =================== fallback plain kernels (same device code, kernel-boundary barriers) ===================
__global__ __launch_bounds__(TPB, 4) void fb_ell(const float* __restrict__ adj,
                                                 int* __restrict__ ell, int* __restrict__ cnt) {
  d_ell(blockIdx.x, threadIdx.x, adj, ell, cnt);
}
__global__ __launch_bounds__(TPB, 4) void fb_ggemm(const float* __restrict__ WT,
                                                   const float* __restrict__ bias,
                                                   const float* __restrict__ xs,
                                                   float* __restrict__ hout) {
  __shared__ float Ws[128 * 132];
  __shared__ float As[32 * 132];
  int tid = threadIdx.x;
  size_t rbase = (size_t)blockIdx.x * RPB;
  d_stage_w(tid, WT, Ws);
  d_stage_a(tid, xs, rbase, As);
  __syncthreads();
  d_gemm44(tid, As, Ws, bias, hout, DIM, rbase);
}
__global__ __launch_bounds__(TPB, 4) void fb_spmv(const int* __restrict__ ell,
                                                  const int* __restrict__ cnt,
                                                  const float* __restrict__ hs,
                                                  float* __restrict__ xs) {
  d_spmv(blockIdx.x, threadIdx.x, ell, cnt, hs, xs);
}
__global__ __launch_bounds__(TPB, 4) void fb_colxc(const float* __restrict__ xs,
                                                   float* __restrict__ xc) {
  __shared__ float red[8 * DIM];
  d_colsum(blockIdx.x, threadIdx.x, xs, red, xc);
}
__global__ void fb_xchain(const float* __restrict__ xc, const float* __restrict__ WaT,
                          const float* __restrict__ ba, float* __restrict__ xall) {
  __shared__ float xb[DIM];
  d_xchain(threadIdx.x, xc, WaT, ba, xb, xall);
}
__global__ __launch_bounds__(TPB, 4) void fb_prot(const float* __restrict__ cur,
    float* __restrict__ nxt, const float* __restrict__ cwl, const float* __restrict__ cbp,
    const float* __restrict__ WaT, const float* __restrict__ ba,
    const float* __restrict__ xrow_g, float* __restrict__ xp, int last) {
  __shared__ float U[128 * 132];
  __shared__ float wl[529];
  __shared__ float As[32 * 132];
  __shared__ float hs2[32 * 132];
  __shared__ float xrow[DIM];
  int tid = threadIdx.x, blk = blockIdx.x;
  d_stage_tile(blk, tid, cur, cwl, U, wl);
  if (tid < DIM) xrow[tid] = xrow_g[tid];
  __syncthreads();
  d_conv(tid, U, wl, cbp[0], As);
  __syncthreads();
  d_stage_w(tid, WaT, U);
  __syncthreads();
  d_gemm44(tid, As, U, ba, hs2, 132, 0);
  __syncthreads();
  d_attn(blk, tid, hs2, xrow, nxt, last, As, xp);
}
__global__ void fb_final(const float* __restrict__ xc, const float* __restrict__ xp,
                         const float* __restrict__ Wo, const float* __restrict__ bo,
                         float* __restrict__ out) {
  __shared__ float fs[32];
  d_final(threadIdx.x, xc, xp, Wo, bo, fs, out);
}

// =================== host ===================
extern "C" void kernel_launch(void* const* d_in, const int* in_sizes, int n_in,
                              void* d_out, int out_size, void* d_ws, size_t ws_size,
                              hipStream_t stream) {
  const int*   fp     = (const int*)d_in[0];
  const int*   words  = (const int*)d_in[1];
  const float* adj    = (const float*)d_in[2];
  const float* emb_fp = (const float*)d_in[3];
  const float* emb_w  = (const float*)d_in[4];
  const float* Wg     = (const float*)d_in[5];
  const float* bg     = (const float*)d_in[6];
  const float* cw     = (const float*)d_in[7];
  const float* cb     = (const float*)d_in[8];
  const float* Wa     = (const float*)d_in[9];
  const float* ba     = (const float*)d_in[10];
  const float* Wo     = (const float*)d_in[11];
  const float* bo     = (const float*)d_in[12];
  float* out = (float*)d_out;

  float* ws   = (float*)d_ws;
  float* xs   = ws;                        // [8192,128]
  float* hsbA = ws + (size_t)NF;           // GNN hs (layers 0,2); also protein bufB
  float* hsbB = ws + 2 * (size_t)NF;       // GNN hs (layer 1)
  float* bufA = ws + 3 * (size_t)NF;       // protein xsp ping (gathered words)
  int*   ell  = (int*)(ws + 4 * (size_t)NF);
  int*   cnt  = ell + (size_t)NATOMS * CAP;
  float* xc   = (float*)(cnt + NATOMS);    // [128]
  float* xp   = xc + DIM;                  // [128]
  float* xall = xp + DIM;                  // [3,128]
  float* WgT  = xall + 3 * DIM;            // [3,128,128]
  float* WaT  = WgT + 3 * DIM * DIM;       // [128,128]
  float* bufB = hsbA;

  k_prep<<<dim3(2113), 256, 0, stream>>>(fp, words, emb_fp, emb_w, Wg, Wa,
                                         xs, bufA, WgT, WaT, xc, xp);

  int mg = 0, mp = 0;
  hipError_t e1 = hipOccupancyMaxActiveBlocksPerMultiprocessor(
      &mg, reinterpret_cast<const void*>(kg), TPB, 0);
  hipError_t e2 = hipOccupancyMaxActiveBlocksPerMultiprocessor(
      &mp, reinterpret_cast<const void*>(kp), TPB, 0);
  bool coop = (e1 == hipSuccess && e2 == hipSuccess && mg >= 1 && mp >= 1);

  if (coop) {
    void* ag[] = {(void*)&adj, (void*)&WgT, (void*)&bg, (void*)&WaT, (void*)&ba,
                  (void*)&ell, (void*)&cnt, (void*)&xs, (void*)&hsbA, (void*)&hsbB,
                  (void*)&xc, (void*)&xall};
    if (hipLaunchCooperativeKernel((void*)kg, dim3(NB), dim3(TPB), ag, 0, stream)
        != hipSuccess) {
      coop = false;
    } else {
      void* ap[] = {(void*)&cw, (void*)&cb, (void*)&WaT, (void*)&ba, (void*)&xall,
                    (void*)&xc, (void*)&Wo, (void*)&bo, (void*)&bufA, (void*)&bufB,
                    (void*)&xp, (void*)&out};
      if (hipLaunchCooperativeKernel((void*)kp, dim3(NB), dim3(TPB), ap, 0, stream)
          != hipSuccess)
        coop = false;
    }
  }

  if (!coop) {
    // full recompute via plain kernels (re-prep re-zeroes accumulators & re-gathers)
    k_prep<<<dim3(2113), 256, 0, stream>>>(fp, words, emb_fp, emb_w, Wg, Wa,
                                           xs, bufA, WgT, WaT, xc, xp);
    fb_ell<<<dim3(NB), TPB, 0, stream>>>(adj, ell, cnt);
    for (int l = 0; l < 3; ++l) {
      float* ho = (l == 1) ? hsbB : hsbA;
      fb_ggemm<<<dim3(NB), TPB, 0, stream>>>(WgT + (size_t)l * DIM * DIM,
                                             bg + l * DIM, xs, ho);
      fb_spmv<<<dim3(NB), TPB, 0, stream>>>(ell, cnt, ho, xs);
    }
    fb_colxc<<<dim3(NB), TPB, 0, stream>>>(xs, xc);
    fb_xchain<<<dim3(1), 128, 0, stream>>>(xc, WaT, ba, xall);
    const float* cur = bufA; float* nxt = bufB;
    for (int l = 0; l < 3; ++l) {
      fb_prot<<<dim3(NB), TPB, 0, stream>>>(cur, nxt, cw + l * 529, cb + l, WaT, ba,
                                            xall + l * DIM, xp, l == 2 ? 1 : 0);
      const float* t = cur; cur = nxt; nxt = (float*)t;
    }
    fb_final<<<dim3(1), 256, 0, stream>>>(xc, xp, Wo, bo, out);
  }
}

// Round 6
// 269.928 us; speedup vs baseline: 1.0750x; 1.0750x over previous
//
#include <hip/hip_runtime.h>
#include <hip/hip_cooperative_groups.h>
#include <math.h>

namespace cg = cooperative_groups;

#define DIM 128
#define NATOMS 8192
#define LPROT 8192
#define CAP 64
#define NF (NATOMS*DIM)
#define NB 256
#define RPB 32
#define TPB 1024

// =================== device phase functions ===================

// stage W^T (row-major [k][j], 128x128 global) into LDS [128][132]
__device__ __forceinline__ void d_stage_w(int tid, const float* __restrict__ WT, float* Ws) {
  for (int i = tid; i < 4096; i += TPB) {
    int r = i >> 5, c = i & 31;
    *(float4*)&Ws[r * 132 + c * 4] = *(const float4*)&WT[r * DIM + c * 4];
  }
}

// stage own 32 rows of A into LDS [32][132]
__device__ __forceinline__ void d_stage_a(int tid, const float* __restrict__ A,
                                          size_t rbase, float* As) {
  for (int i = tid; i < 1024; i += TPB) {
    int r = i >> 5, c = i & 31;
    *(float4*)&As[r * 132 + c * 4] = *(const float4*)&A[(rbase + r) * DIM + c * 4];
  }
}

// 256-thread 4x4-tile gemm: out[r][j] = relu(sum_k As[r][k]*Ws[k][j] + bias[j])
__device__ __forceinline__ void d_gemm44(int tid, const float* As, const float* Ws,
                                         const float* __restrict__ bias,
                                         float* out, int ostr, size_t obase) {
  if (tid < 256) {
    int j0 = (tid & 31) * 4, r0 = (tid >> 5) * 4;
    float acc[4][4];
    float4 b4 = *(const float4*)&bias[j0];
    #pragma unroll
    for (int ri = 0; ri < 4; ++ri) {
      acc[ri][0] = b4.x; acc[ri][1] = b4.y; acc[ri][2] = b4.z; acc[ri][3] = b4.w;
    }
    for (int k4 = 0; k4 < 32; ++k4) {
      float a[4][4], w[4][4];
      #pragma unroll
      for (int ri = 0; ri < 4; ++ri)
        *(float4*)a[ri] = *(const float4*)&As[(r0 + ri) * 132 + k4 * 4];
      #pragma unroll
      for (int kk = 0; kk < 4; ++kk)
        *(float4*)w[kk] = *(const float4*)&Ws[(k4 * 4 + kk) * 132 + j0];
      #pragma unroll
      for (int ri = 0; ri < 4; ++ri)
        #pragma unroll
        for (int kk = 0; kk < 4; ++kk) {
          acc[ri][0] += a[ri][kk] * w[kk][0];
          acc[ri][1] += a[ri][kk] * w[kk][1];
          acc[ri][2] += a[ri][kk] * w[kk][2];
          acc[ri][3] += a[ri][kk] * w[kk][3];
        }
    }
    #pragma unroll
    for (int ri = 0; ri < 4; ++ri) {
      float4 o;
      o.x = fmaxf(acc[ri][0], 0.f); o.y = fmaxf(acc[ri][1], 0.f);
      o.z = fmaxf(acc[ri][2], 0.f); o.w = fmaxf(acc[ri][3], 0.f);
      *(float4*)&out[(obase + r0 + ri) * (size_t)ostr + j0] = o;
    }
  }
}

// spmv over own 32 rows: xs[row] += sum of neighbor hs rows; 16 waves x 2 rows
__device__ __forceinline__ void d_spmv(int blk, int tid, const int* __restrict__ ell,
                                       const int* __restrict__ cnt,
                                       const float* __restrict__ hs, float* __restrict__ xs) {
  int wv = tid >> 6, lane = tid & 63;
  for (int rr = 0; rr < 2; ++rr) {
    size_t row = (size_t)blk * RPB + wv * 2 + rr;
    int n = cnt[row];
    const int* er = ell + row * CAP;
    float2 a2 = *(const float2*)&xs[row * DIM + lane * 2];
    int t = 0;
    for (; t + 4 <= n; t += 4) {
      int j0 = er[t], j1 = er[t + 1], j2 = er[t + 2], j3 = er[t + 3];
      float2 h0 = *(const float2*)&hs[(size_t)j0 * DIM + lane * 2];
      float2 h1 = *(const float2*)&hs[(size_t)j1 * DIM + lane * 2];
      float2 h2 = *(const float2*)&hs[(size_t)j2 * DIM + lane * 2];
      float2 h3 = *(const float2*)&hs[(size_t)j3 * DIM + lane * 2];
      a2.x += (h0.x + h1.x) + (h2.x + h3.x);
      a2.y += (h0.y + h1.y) + (h2.y + h3.y);
    }
    for (; t < n; ++t) {
      float2 h = *(const float2*)&hs[(size_t)er[t] * DIM + lane * 2];
      a2.x += h.x; a2.y += h.y;
    }
    *(float2*)&xs[row * DIM + lane * 2] = a2;
  }
}

// column-sum of own 32 rows -> atomicAdd into dst[128]; red = 8*128 shared
__device__ __forceinline__ void d_colsum(int blk, int tid, const float* __restrict__ src,
                                         float* red, float* __restrict__ dst) {
  int c = tid & 127, h = tid >> 7;
  size_t rbase = (size_t)blk * RPB;
  float s = 0.f;
  for (int r = h; r < RPB; r += 8) s += src[(rbase + r) * DIM + c];
  red[h * DIM + c] = s;
  __syncthreads();
  if (h == 0) {
    float t2 = 0.f;
    #pragma unroll
    for (int w = 0; w < 8; ++w) t2 += red[w * DIM + c];
    atomicAdd(&dst[c], t2);
  }
}

// x-chain: 3x relu(x @ Wa^T + ba) -> xall[0..2]; xb = shared >=128
__device__ __forceinline__ void d_xchain(int tid, const float* __restrict__ xc,
                                         const float* __restrict__ WaT,
                                         const float* __restrict__ ba,
                                         float* xb, float* __restrict__ xall) {
  if (tid < DIM) xb[tid] = xc[tid];
  __syncthreads();
  for (int i = 0; i < 3; ++i) {
    float a = 0.f;
    if (tid < DIM) {
      a = ba[tid];
      for (int k = 0; k < DIM; ++k) a += xb[k] * WaT[k * DIM + tid];
      a = fmaxf(a, 0.f);
    }
    __syncthreads();
    if (tid < DIM) { xb[tid] = a; xall[i * DIM + tid] = a; }
    __syncthreads();
  }
}

// stage conv input tile (54x156 zero-padded) + weights
__device__ __forceinline__ void d_stage_tile(int blk, int tid, const float* __restrict__ cur,
                                             const float* __restrict__ cwl,
                                             float* U, float* wl) {
  for (int i = tid; i < 529; i += TPB) wl[i] = cwl[i];
  int l0 = blk * RPB;
  for (int i = tid; i < 54 * 156; i += TPB) {
    int ll = i / 156, dd = i % 156;
    int gl = l0 - 11 + ll, gd = dd - 11;
    float v = 0.f;
    if (gl >= 0 && gl < LPROT && (unsigned)gd < DIM)
      v = cur[(size_t)gl * DIM + gd];
    U[i] = v;
  }
}

// 23x23 conv: thread -> row (tid>>5), 4 cols at (tid&31)*4; writes relu to As[32][132]
__device__ __forceinline__ void d_conv(int tid, const float* U, const float* wl,
                                       float cbias, float* As) {
  int ro = tid >> 5, d0 = (tid & 31) * 4;
  float acc[4] = {0.f, 0.f, 0.f, 0.f};
  for (int a = 0; a < 23; ++a) {
    float r[26];
    #pragma unroll
    for (int q = 0; q < 6; ++q)
      *(float4*)&r[4 * q] = *(const float4*)&U[(ro + a) * 156 + d0 + 4 * q];
    r[24] = U[(ro + a) * 156 + d0 + 24];
    r[25] = U[(ro + a) * 156 + d0 + 25];
    #pragma unroll
    for (int b = 0; b < 23; ++b) {
      float wb = wl[a * 23 + b];
      #pragma unroll
      for (int m = 0; m < 4; ++m) acc[m] += r[b + m] * wb;
    }
  }
  #pragma unroll
  for (int m = 0; m < 4; ++m)
    As[ro * 132 + d0 + m] = fmaxf(acc[m] + cbias, 0.f);
}

// attention: weights = tanh(x . hs2_row); write nxt (or accumulate colsum -> xp if last)
__device__ __forceinline__ void d_attn(int blk, int tid, const float* hs2, const float* xrow,
                                       float* __restrict__ nxt, int last,
                                       float* red, float* __restrict__ xp) {
  int wv = tid >> 6, lane = tid & 63;
  size_t rbase = (size_t)blk * RPB;
  float x0 = xrow[lane * 2], x1 = xrow[lane * 2 + 1];
  float cx = 0.f, cy = 0.f;
  #pragma unroll
  for (int rr = 0; rr < 2; ++rr) {
    int row = wv * 2 + rr;
    float2 h = *(const float2*)&hs2[row * 132 + lane * 2];
    float p = h.x * x0 + h.y * x1;
    #pragma unroll
    for (int s = 32; s > 0; s >>= 1) p += __shfl_xor(p, s, 64);
    float wgt = tanhf(p);
    if (!last) {
      float2 o; o.x = wgt * h.x; o.y = wgt * h.y;
      *(float2*)&nxt[(rbase + row) * DIM + lane * 2] = o;
    } else { cx += wgt * h.x; cy += wgt * h.y; }
  }
  if (last) {
    red[wv * DIM + lane * 2] = cx;
    red[wv * DIM + lane * 2 + 1] = cy;
    __syncthreads();
    if (wv == 0) {
      float sx = 0.f, sy = 0.f;
      #pragma unroll
      for (int w = 0; w < 16; ++w) {
        sx += red[w * DIM + lane * 2];
        sy += red[w * DIM + lane * 2 + 1];
      }
      atomicAdd(&xp[lane * 2], sx);
      atomicAdd(&xp[lane * 2 + 1], sy);
    }
  }
}

// final softmax([xc|xp] @ Wo^T + bo) -> out[2]; fs = shared >=32
__device__ __forceinline__ void d_final(int tid, const float* __restrict__ xc,
                                        const float* __restrict__ xp,
                                        const float* __restrict__ Wo,
                                        const float* __restrict__ bo,
                                        float* fs, float* __restrict__ out) {
  int wv = tid >> 6, lane = tid & 63;
  float p0 = 0.f, p1 = 0.f;
  if (tid < 256) {
    float y = (tid < DIM) ? xc[tid] : xp[tid - DIM];
    p0 = y * Wo[tid];
    p1 = y * Wo[256 + tid];
  }
  #pragma unroll
  for (int s = 32; s > 0; s >>= 1) { p0 += __shfl_xor(p0, s, 64); p1 += __shfl_xor(p1, s, 64); }
  if (tid < 256 && lane == 0) { fs[wv] = p0; fs[16 + wv] = p1; }
  __syncthreads();
  if (tid == 0) {
    float l0 = bo[0], l1 = bo[1];
    #pragma unroll
    for (int w = 0; w < 4; ++w) { l0 += fs[w]; l1 += fs[16 + w]; }
    float m = fmaxf(l0, l1);
    float e0 = expf(l0 - m), e1 = expf(l1 - m);
    out[0] = e0 / (e0 + e1);
    out[1] = e1 / (e0 + e1);
  }
}

// =================== kernel 1: prep+build (plain): ELL + gathers + transposes + zero ===================
__global__ __launch_bounds__(256) void k_prep_build(
    const int* __restrict__ fp, const int* __restrict__ words,
    const float* __restrict__ emb_fp, const float* __restrict__ emb_w,
    const float* __restrict__ Wg, const float* __restrict__ Wa,
    const float* __restrict__ adj,
    float* __restrict__ xs, float* __restrict__ xsp,
    float* __restrict__ WgT, float* __restrict__ WaT,
    int* __restrict__ ell, int* __restrict__ cnt,
    float* __restrict__ xc, float* __restrict__ xp) {
  int b = blockIdx.x, tid = threadIdx.x;
  if (b < 2048) {                       // ELL: 4 waves, 1 row/wave, 8-deep MLP
    int wv = tid >> 6, lane = tid & 63;
    int row = b * 4 + wv;
    const float4* rp = (const float4*)(adj + (size_t)row * NATOMS);
    int* er = ell + (size_t)row * CAP;
    int c = 0;
    float4 buf[8];
    #pragma unroll
    for (int u = 0; u < 8; ++u) buf[u] = rp[u * 64 + lane];
    for (int it = 0; it < 32; it += 8) {
      float4 nb[8];
      if (it + 8 < 32) {
        #pragma unroll
        for (int u = 0; u < 8; ++u) nb[u] = rp[(it + 8 + u) * 64 + lane];
      }
      #pragma unroll
      for (int u = 0; u < 8; ++u) {
        float f[4] = {buf[u].x, buf[u].y, buf[u].z, buf[u].w};
        #pragma unroll
        for (int j = 0; j < 4; ++j) {
          bool nz = (f[j] != 0.0f);
          unsigned long long m = __ballot(nz);
          if (nz) {
            int pos = c + __popcll(m & ((1ull << lane) - 1ull));
            if (pos < CAP) er[pos] = (it + u) * 256 + lane * 4 + j;
          }
          c += __popcll(m);
        }
      }
      #pragma unroll
      for (int u = 0; u < 8; ++u) buf[u] = nb[u];
    }
    if (lane == 0) cnt[row] = c > CAP ? CAP : c;
  } else if (b < 3072) {                // gather atom embeddings
    int i = (b - 2048) * 256 + tid;
    int row = i >> 5, c4 = i & 31;
    ((float4*)(xs + (size_t)row * DIM))[c4] =
        ((const float4*)(emb_fp + (size_t)fp[row] * DIM))[c4];
  } else if (b < 4096) {                // gather word embeddings
    int i = (b - 3072) * 256 + tid;
    int row = i >> 5, c4 = i & 31;
    ((float4*)(xsp + (size_t)row * DIM))[c4] =
        ((const float4*)(emb_w + (size_t)words[row] * DIM))[c4];
  } else if (b < 4160) {                // transpose Wg[0..2], Wa
    __shared__ float tile[32][33];
    int sub = b - 4096;
    int m = sub >> 4, t = sub & 15;
    int tx = t & 3, ty = t >> 2;
    const float* src = (m < 3) ? Wg + m * DIM * DIM : Wa;
    float*       dst = (m < 3) ? WgT + m * DIM * DIM : WaT;
    int x = tid & 31, y0 = tid >> 5;
    int xg = tx * 32 + x;
    for (int i = y0; i < 32; i += 8)
      tile[i][x] = src[(ty * 32 + i) * DIM + xg];
    __syncthreads();
    int xo = ty * 32 + x;
    for (int i = y0; i < 32; i += 8)
      dst[(tx * 32 + i) * DIM + xo] = tile[x][i];
  } else {                              // zero atomic accumulators
    if (tid < DIM) { xc[tid] = 0.f; xp[tid] = 0.f; }
  }
}

// =================== kernel 2: merged cooperative GNN + protein chain ===================
__global__ __launch_bounds__(TPB, 4) void kmain(
    const float* __restrict__ WgT, const float* __restrict__ bg,
    const float* __restrict__ WaT, const float* __restrict__ ba,
    const int* __restrict__ ell, const int* __restrict__ cnt,
    const float* __restrict__ cw, const float* __restrict__ cb,
    const float* __restrict__ Wo, const float* __restrict__ bo,
    float* __restrict__ xs, float* __restrict__ hsbA, float* __restrict__ hsbB,
    float* __restrict__ bufA, float* __restrict__ bufB,
    float* __restrict__ xc, float* __restrict__ xp,
    float* __restrict__ xall, float* __restrict__ out) {
  cg::grid_group grid = cg::this_grid();
  __shared__ float Ws[128 * 132];   // union: W^T staging / conv tile (54*156=8424)
  __shared__ float As[32 * 132];
  __shared__ float hs2[32 * 132];
  __shared__ float red[8 * DIM];
  __shared__ float wl[529];
  __shared__ float xrow[DIM];
  __shared__ float fs[32];
  int tid = threadIdx.x, blk = blockIdx.x;
  size_t rbase = (size_t)blk * RPB;

  // ---- GNN: 3x (gemm -> grid.sync -> spmv) ----
  for (int layer = 0; layer < 3; ++layer) {
    float* hout = (layer == 1) ? hsbB : hsbA;
    d_stage_w(tid, WgT + (size_t)layer * DIM * DIM, Ws);
    d_stage_a(tid, xs, rbase, As);
    __syncthreads();
    d_gemm44(tid, As, Ws, bg + layer * DIM, hout, DIM, rbase);
    grid.sync();
    d_spmv(blk, tid, ell, cnt, hout, xs);
    __syncthreads();
  }
  d_colsum(blk, tid, xs, red, xc);
  grid.sync();
  if (blk == 0) d_xchain(tid, xc, WaT, ba, red, xall);
  grid.sync();

  // ---- protein: 3x (conv -> gemm -> attn) ----
  const float* cur = bufA;
  float* nxt = bufB;
  for (int layer = 0; layer < 3; ++layer) {
    d_stage_tile(blk, tid, cur, cw + layer * 529, Ws, wl);
    if (tid < DIM) xrow[tid] = xall[layer * DIM + tid];
    __syncthreads();
    d_conv(tid, Ws, wl, cb[layer], As);
    __syncthreads();                 // conv done reading Ws
    d_stage_w(tid, WaT, Ws);
    __syncthreads();
    d_gemm44(tid, As, Ws, ba, hs2, 132, 0);
    __syncthreads();
    d_attn(blk, tid, hs2, xrow, nxt, layer == 2, As, xp);
    grid.sync();
    const float* t = cur; cur = nxt; nxt = (float*)t;
  }
  if (blk == 0) d_final(tid, xc, xp, Wo, bo, fs, out);
}

// =================== fallback plain kernels ===================
__global__ __launch_bounds__(TPB, 4) void fb_ggemm(const float* __restrict__ WT,
                                                   const float* __restrict__ bias,
                                                   const float* __restrict__ xs,
                                                   float* __restrict__ hout) {
  __shared__ float Ws[128 * 132];
  __shared__ float As[32 * 132];
  int tid = threadIdx.x;
  size_t rbase = (size_t)blockIdx.x * RPB;
  d_stage_w(tid, WT, Ws);
  d_stage_a(tid, xs, rbase, As);
  __syncthreads();
  d_gemm44(tid, As, Ws, bias, hout, DIM, rbase);
}
__global__ __launch_bounds__(TPB, 4) void fb_spmv(const int* __restrict__ ell,
                                                  const int* __restrict__ cnt,
                                                  const float* __restrict__ hs,
                                                  float* __restrict__ xs) {
  d_spmv(blockIdx.x, threadIdx.x, ell, cnt, hs, xs);
}
__global__ __launch_bounds__(TPB, 4) void fb_colxc(const float* __restrict__ xs,
                                                   float* __restrict__ xc) {
  __shared__ float red[8 * DIM];
  d_colsum(blockIdx.x, threadIdx.x, xs, red, xc);
}
__global__ void fb_xchain(const float* __restrict__ xc, const float* __restrict__ WaT,
                          const float* __restrict__ ba, float* __restrict__ xall) {
  __shared__ float xb[DIM];
  d_xchain(threadIdx.x, xc, WaT, ba, xb, xall);
}
__global__ __launch_bounds__(TPB, 4) void fb_prot(const float* __restrict__ cur,
    float* __restrict__ nxt, const float* __restrict__ cwl, const float* __restrict__ cbp,
    const float* __restrict__ WaT, const float* __restrict__ ba,
    const float* __restrict__ xrow_g, float* __restrict__ xp, int last) {
  __shared__ float U[128 * 132];
  __shared__ float wl[529];
  __shared__ float As[32 * 132];
  __shared__ float hs2[32 * 132];
  __shared__ float xrow[DIM];
  int tid = threadIdx.x, blk = blockIdx.x;
  d_stage_tile(blk, tid, cur, cwl, U, wl);
  if (tid < DIM) xrow[tid] = xrow_g[tid];
  __syncthreads();
  d_conv(tid, U, wl, cbp[0], As);
  __syncthreads();
  d_stage_w(tid, WaT, U);
  __syncthreads();
  d_gemm44(tid, As, U, ba, hs2, 132, 0);
  __syncthreads();
  d_attn(blk, tid, hs2, xrow, nxt, last, As, xp);
}
__global__ void fb_final(const float* __restrict__ xc, const float* __restrict__ xp,
                         const float* __restrict__ Wo, const float* __restrict__ bo,
                         float* __restrict__ out) {
  __shared__ float fs[32];
  d_final(threadIdx.x, xc, xp, Wo, bo, fs, out);
}

// =================== host ===================
extern "C" void kernel_launch(void* const* d_in, const int* in_sizes, int n_in,
                              void* d_out, int out_size, void* d_ws, size_t ws_size,
                              hipStream_t stream) {
  const int*   fp     = (const int*)d_in[0];
  const int*   words  = (const int*)d_in[1];
  const float* adj    = (const float*)d_in[2];
  const float* emb_fp = (const float*)d_in[3];
  const float* emb_w  = (const float*)d_in[4];
  const float* Wg     = (const float*)d_in[5];
  const float* bg     = (const float*)d_in[6];
  const float* cw     = (const float*)d_in[7];
  const float* cb     = (const float*)d_in[8];
  const float* Wa     = (const float*)d_in[9];
  const float* ba     = (const float*)d_in[10];
  const float* Wo     = (const float*)d_in[11];
  const float* bo     = (const float*)d_in[12];
  float* out = (float*)d_out;

  float* ws   = (float*)d_ws;
  float* xs   = ws;                        // [8192,128]
  float* hsbA = ws + (size_t)NF;           // GNN hs (layers 0,2); protein bufB
  float* hsbB = ws + 2 * (size_t)NF;       // GNN hs (layer 1)
  float* bufA = ws + 3 * (size_t)NF;       // protein xsp ping (gathered words)
  int*   ell  = (int*)(ws + 4 * (size_t)NF);
  int*   cnt  = ell + (size_t)NATOMS * CAP;
  float* xc   = (float*)(cnt + NATOMS);    // [128]
  float* xp   = xc + DIM;                  // [128]
  float* xall = xp + DIM;                  // [3,128]
  float* WgT  = xall + 3 * DIM;            // [3,128,128]
  float* WaT  = WgT + 3 * DIM * DIM;       // [128,128]
  float* bufB = hsbA;

  k_prep_build<<<dim3(4161), 256, 0, stream>>>(
      fp, words, emb_fp, emb_w, Wg, Wa, adj,
      xs, bufA, WgT, WaT, ell, cnt, xc, xp);

  int mg = 0;
  hipError_t e1 = hipOccupancyMaxActiveBlocksPerMultiprocessor(
      &mg, reinterpret_cast<const void*>(kmain), TPB, 0);
  bool coop = (e1 == hipSuccess && mg >= 1);

  if (coop) {
    void* a[] = {(void*)&WgT, (void*)&bg, (void*)&WaT, (void*)&ba,
                 (void*)&ell, (void*)&cnt, (void*)&cw, (void*)&cb,
                 (void*)&Wo, (void*)&bo, (void*)&xs, (void*)&hsbA, (void*)&hsbB,
                 (void*)&bufA, (void*)&bufB, (void*)&xc, (void*)&xp,
                 (void*)&xall, (void*)&out};
    if (hipLaunchCooperativeKernel((void*)kmain, dim3(NB), dim3(TPB), a, 0, stream)
        != hipSuccess)
      coop = false;
  }

  if (!coop) {
    for (int l = 0; l < 3; ++l) {
      float* ho = (l == 1) ? hsbB : hsbA;
      fb_ggemm<<<dim3(NB), TPB, 0, stream>>>(WgT + (size_t)l * DIM * DIM,
                                             bg + l * DIM, xs, ho);
      fb_spmv<<<dim3(NB), TPB, 0, stream>>>(ell, cnt, ho, xs);
    }
    fb_colxc<<<dim3(NB), TPB, 0, stream>>>(xs, xc);
    fb_xchain<<<dim3(1), 128, 0, stream>>>(xc, WaT, ba, xall);
    const float* cur = bufA; float* nxt = bufB;
    for (int l = 0; l < 3; ++l) {
      fb_prot<<<dim3(NB), TPB, 0, stream>>>(cur, nxt, cw + l * 529, cb + l, WaT, ba,
                                            xall + l * DIM, xp, l == 2 ? 1 : 0);
      const float* t = cur; cur = nxt; nxt = (float*)t;
    }
    fb_final<<<dim3(1), 256, 0, stream>>>(xc, xp, Wo, bo, out);
  }
}